// Round 6
// baseline (834.213 us; speedup 1.0000x reference)
//
#include <hip/hip_runtime.h>
#include <hip/hip_bf16.h>
#include <cstdint>

#define B_ 512
#define S_ 512
#define V_ 5000
#define E_ 100
#define HD_ 64
#define T_ 25
#define START_ 1
#define STOP_ 2

typedef __attribute__((ext_vector_type(8))) short short8;
typedef __attribute__((ext_vector_type(4))) float f32x4;
typedef __attribute__((ext_vector_type(8))) _Float16 f16x8;

__device__ inline float sigm(float x) { return 1.0f / (1.0f + __expf(-x)); }
__device__ inline float tanh_(float x) { return 1.0f - 2.0f / (1.0f + __expf(2.0f * x)); }

__device__ inline f32x4 mm16(f16x8 a, f16x8 b, f32x4 c) {
  return __builtin_amdgcn_mfma_f32_16x16x32_f16(a, b, c, 0, 0, 0);
}

// ---------------- prep: Wcomb[d][256][192] f16 = [Whh | Wih | 0] -------------
__global__ __launch_bounds__(256) void k_prep_w(const float* __restrict__ Whh_f,
                                                const float* __restrict__ Wih_f,
                                                const float* __restrict__ Whh_b,
                                                const float* __restrict__ Wih_b,
                                                _Float16* __restrict__ Wcomb) {
  int idx = blockIdx.x * 256 + threadIdx.x;
  if (idx >= 2 * 256 * 192) return;
  int d = idx / (256 * 192);
  int rem = idx % (256 * 192);
  int u = rem / 192, k = rem % 192;
  const float* Whh = d ? Whh_b : Whh_f;
  const float* Wih = d ? Wih_b : Wih_f;
  float v = (k < HD_) ? Whh[u * HD_ + k]
                      : ((k < HD_ + E_) ? Wih[u * E_ + (k - HD_)] : 0.f);
  Wcomb[idx] = (_Float16)v;
}

// ---------------- prep: embP[V][112] f16 (cols >= 100 zero) -------------------
__global__ __launch_bounds__(256) void k_prep_e(const float* __restrict__ embed,
                                                _Float16* __restrict__ embP) {
  int idx = blockIdx.x * 256 + threadIdx.x;
  if (idx >= V_ * 112) return;
  int v = idx / 112, e = idx % 112;
  embP[idx] = (e < E_) ? (_Float16)embed[v * E_ + e] : (_Float16)0.f;
}

// ---------------- prep: WoutPad[32][128] bf16 (rows >= 25 zero) ---------------
__global__ __launch_bounds__(256) void k_prep_o(const float* __restrict__ Wout,
                                                __hip_bfloat16* __restrict__ WoutP) {
  int idx = blockIdx.x * 256 + threadIdx.x;
  if (idx < 32 * 128) {
    int r = idx >> 7, c = idx & 127;
    float v = (r < T_) ? Wout[r * 128 + c] : 0.f;
    WoutP[idx] = __float2bfloat16(v);
  }
}

// ---------------- K2: BiLSTM recurrence via MFMA ------------------------------
// Block = gang of 16 sequences, one dir; 4 waves; wave w owns units 16w..16w+15
// across all 4 gates (in-lane gate combine). Per step: Z = [H|emb]·Wcomb^T via
// 24 mfma_f32_16x16x32_f16 per wave (K=192). B-frags register/AGPR-resident
// (MFMA reads AGPR natively -> no accvgpr_read tax). Double-buffered H/Ae LDS,
// one barrier/step; emb gather prefetched one step ahead.
__global__ __launch_bounds__(256, 1) void k_lstm(
    const int* __restrict__ sentences,
    const _Float16* __restrict__ embP,     // [V][112]
    const _Float16* __restrict__ Wcomb,    // [2][256][192]
    const float* __restrict__ bih_f, const float* __restrict__ bhh_f,
    const float* __restrict__ bih_b, const float* __restrict__ bhh_b,
    const float* __restrict__ h0, const float* __restrict__ c0,
    __hip_bfloat16* __restrict__ feat) {
  int tid = threadIdx.x;
  int w = tid >> 6, l = tid & 63;
  int row = tid >> 4, tr = tid & 15;       // staging role: 16 thr per seq-row
  int grp = blockIdx.x & 31, d = blockIdx.x >> 5;
  int sbase = grp * 16;
  const float* bih = d ? bih_b : bih_f;
  const float* bhh = d ? bhh_b : bhh_f;

  // LDS: H rows padded to 72 f16 (bank-shift 4/row -> 2-way max, free);
  //      Ae rows padded to 136 f16 (68 words -> 2-way max), 16B-aligned rows.
  __shared__ __align__(16) _Float16 Hs[2][16][72];
  __shared__ __align__(16) _Float16 Ae[2][16][136];

  int mrow = l & 15, kg = l >> 4;
  int ucol = w * 16 + mrow;                // unit this lane owns
  int r0 = kg * 4;                         // lane's first seq row (D-layout)

  // B-fragments: Wcomb[d][g*64+ucol][kt*32 + kg*8 .. +8], 24 frags (96 regs)
  f16x8 Bf[4][6];
  const _Float16* Wd = Wcomb + (size_t)d * 256 * 192;
#pragma unroll
  for (int g = 0; g < 4; g++) {
    const _Float16* rp = Wd + (size_t)(g * 64 + ucol) * 192;
#pragma unroll
    for (int kt = 0; kt < 6; kt++)
      Bf[g][kt] = *(const f16x8*)(rp + kt * 32 + kg * 8);
  }
  float bg[4];
#pragma unroll
  for (int g = 0; g < 4; g++) {
    int u = g * 64 + ucol;
    bg[g] = bih[u] + bhh[u];
  }
  float cc[4];
#pragma unroll
  for (int q = 0; q < 4; q++)
    cc[q] = c0[(size_t)(d * B_ + sbase + r0 + q) * HD_ + ucol];

  // stage H[0] = f16(h0), zero Ae pad cols [112,136) both buffers
  for (int idx = tid; idx < 16 * HD_; idx += 256)
    Hs[0][idx >> 6][idx & 63] =
        (_Float16)h0[(size_t)(d * B_ + sbase + (idx >> 6)) * HD_ + (idx & 63)];
  for (int idx = tid; idx < 2 * 16 * 24; idx += 256) {
    int bsel = idx / (16 * 24);
    int rem = idx % (16 * 24);
    Ae[bsel][rem / 24][112 + rem % 24] = (_Float16)0.f;
  }

  const int* sent_row = sentences + (size_t)(sbase + row) * S_;
  int tt0 = d ? (S_ - 1) : 0, stp = d ? -1 : 1;
  int tok0 = sent_row[tt0];
  if (tr < 14) {
    uint4 g0 = ((const uint4*)embP)[(size_t)tok0 * 14 + tr];
    *(uint4*)(&Ae[0][row][tr * 8]) = g0;
  }
  int tokN = sent_row[tt0 + stp];          // token for t=1
  __syncthreads();

  for (int t = 0; t < S_; ++t) {
    int cur = t & 1, nxt = cur ^ 1;
    int tt = tt0 + stp * t;
    // prefetch emb(t+1) into regs (consumed at step end -> latency covered)
    uint4 gv;
    bool havegv = (t + 1 < S_) && (tr < 14);
    if (havegv) gv = ((const uint4*)embP)[(size_t)tokN * 14 + tr];
    int tokN2 = tokN;
    if (t + 2 < S_) tokN2 = sent_row[tt + 2 * stp];

    // A-fragments: row = mrow (seq), k-slices from H then Ae
    f16x8 Ah0 = *(const f16x8*)(&Hs[cur][mrow][kg * 8]);
    f16x8 Ah1 = *(const f16x8*)(&Hs[cur][mrow][32 + kg * 8]);
    f16x8 Ae0 = *(const f16x8*)(&Ae[cur][mrow][kg * 8]);
    f16x8 Ae1 = *(const f16x8*)(&Ae[cur][mrow][32 + kg * 8]);
    f16x8 Ae2 = *(const f16x8*)(&Ae[cur][mrow][64 + kg * 8]);
    f16x8 Ae3 = *(const f16x8*)(&Ae[cur][mrow][96 + kg * 8]);

    f32x4 acc[4];
#pragma unroll
    for (int g = 0; g < 4; g++) {
      acc[g] = (f32x4){bg[g], bg[g], bg[g], bg[g]};
      acc[g] = mm16(Ah0, Bf[g][0], acc[g]);
      acc[g] = mm16(Ah1, Bf[g][1], acc[g]);
      acc[g] = mm16(Ae0, Bf[g][2], acc[g]);
      acc[g] = mm16(Ae1, Bf[g][3], acc[g]);
      acc[g] = mm16(Ae2, Bf[g][4], acc[g]);
      acc[g] = mm16(Ae3, Bf[g][5], acc[g]);
    }
    // in-lane gates: lane covers (unit=ucol, seqs r0..r0+3)
#pragma unroll
    for (int q = 0; q < 4; q++) {
      float zi = acc[0][q], zf = acc[1][q], zg = acc[2][q], zo = acc[3][q];
      float c2 = sigm(zf) * cc[q] + sigm(zi) * tanh_(zg);
      cc[q] = c2;
      float hh = sigm(zo) * tanh_(c2);
      Hs[nxt][r0 + q][ucol] = (_Float16)hh;
      feat[(((size_t)(sbase + r0 + q)) * S_ + tt) * 128 + d * 64 + ucol] =
          __float2bfloat16(hh);
    }
    if (havegv) *(uint4*)(&Ae[nxt][row][tr * 8]) = gv;
    tokN = tokN2;
    __syncthreads();
  }
}

// ---------------- K3: logits = feat . WoutP^T + bout via MFMA -----------------
__global__ __launch_bounds__(256) void k_logits(const __hip_bfloat16* __restrict__ feat,
                                                const __hip_bfloat16* __restrict__ WoutP,
                                                const float* __restrict__ bout,
                                                float* __restrict__ logits) {
  int w = threadIdx.x >> 6, l = threadIdx.x & 63;
  size_t r0 = ((size_t)blockIdx.x * 4 + w) * 16;
  int mrow = l & 15, kg = l >> 4;
  short8 bfr[2][4];
#pragma unroll
  for (int nt = 0; nt < 2; nt++) {
    int n = nt * 16 + mrow;
#pragma unroll
    for (int kb = 0; kb < 4; kb++)
      bfr[nt][kb] = *(const short8*)(WoutP + n * 128 + kb * 32 + kg * 8);
  }
  f32x4 acc[2];
#pragma unroll
  for (int nt = 0; nt < 2; nt++) {
    int col = nt * 16 + mrow;
    float bb = (col < T_) ? bout[col] : 0.f;
    acc[nt] = (f32x4){bb, bb, bb, bb};
  }
#pragma unroll
  for (int kb = 0; kb < 4; kb++) {
    short8 a = *(const short8*)(feat + (r0 + mrow) * 128 + kb * 32 + kg * 8);
    acc[0] = __builtin_amdgcn_mfma_f32_16x16x32_bf16(a, bfr[0][kb], acc[0], 0, 0, 0);
    acc[1] = __builtin_amdgcn_mfma_f32_16x16x32_bf16(a, bfr[1][kb], acc[1], 0, 0, 0);
  }
#pragma unroll
  for (int nt = 0; nt < 2; nt++) {
    int col = nt * 16 + mrow;
    if (col < T_) {
#pragma unroll
      for (int q = 0; q < 4; q++) {
        int rowq = kg * 4 + q;
        logits[(r0 + rowq) * T_ + col] = acc[nt][q];
      }
    }
  }
}

// ---------------- K4: CRF forward, 1 wave = 1 batch elem ---------------------
__global__ __launch_bounds__(64) void k_crf(const float* __restrict__ logits,
                                            const float* __restrict__ trans,
                                            float* __restrict__ totals) {
  int j = threadIdx.x;
  int b = blockIdx.x;
  bool act = j < T_;
  __shared__ __align__(16) float qS[32];
  float Ecol[T_];
#pragma unroll
  for (int i = 0; i < T_; i++)
    Ecol[i] = act ? __expf(trans[i * T_ + j]) : 0.f;
  if (j >= T_ && j < 32) qS[j] = 0.f;
  float tstop = act ? trans[j * T_ + STOP_] : 0.f;
  float prev = act ? 0.f : -INFINITY;
  const float* lg = logits + (size_t)b * S_ * T_;
  float ltn = act ? lg[j] : 0.f;
  asm volatile("s_waitcnt lgkmcnt(0)" ::: "memory");
  for (int t = 0; t < S_; t++) {
    float lt = ltn;
    if (t + 1 < S_) ltn = act ? lg[(size_t)(t + 1) * T_ + j] : 0.f;
    float m = __builtin_bit_cast(float,
        __builtin_amdgcn_readfirstlane(__builtin_bit_cast(int, prev)));
    float q = __expf(prev - m);
    if (act) qS[j] = q;
    asm volatile("s_waitcnt lgkmcnt(0)" ::: "memory");
    const float4* q4 = (const float4*)qS;
    float4 qv0 = q4[0], qv1 = q4[1], qv2 = q4[2], qv3 = q4[3];
    float4 qv4 = q4[4], qv5 = q4[5], qv6 = q4[6];
    float s0, s1, s2, s3;
    s0 = qv0.x * Ecol[0];  s1 = qv0.y * Ecol[1];
    s2 = qv0.z * Ecol[2];  s3 = qv0.w * Ecol[3];
    s0 += qv1.x * Ecol[4];  s1 += qv1.y * Ecol[5];
    s2 += qv1.z * Ecol[6];  s3 += qv1.w * Ecol[7];
    s0 += qv2.x * Ecol[8];  s1 += qv2.y * Ecol[9];
    s2 += qv2.z * Ecol[10]; s3 += qv2.w * Ecol[11];
    s0 += qv3.x * Ecol[12]; s1 += qv3.y * Ecol[13];
    s2 += qv3.z * Ecol[14]; s3 += qv3.w * Ecol[15];
    s0 += qv4.x * Ecol[16]; s1 += qv4.y * Ecol[17];
    s2 += qv4.z * Ecol[18]; s3 += qv4.w * Ecol[19];
    s0 += qv5.x * Ecol[20]; s1 += qv5.y * Ecol[21];
    s2 += qv5.z * Ecol[22]; s3 += qv5.w * Ecol[23];
    s0 += qv6.x * Ecol[24];
    float s = (s0 + s1) + (s2 + s3);
    prev = lt + m + __logf(s);
    if (!act) prev = -INFINITY;
  }
  float v = prev + tstop;
  float m = v;
#pragma unroll
  for (int off = 32; off > 0; off >>= 1)
    m = fmaxf(m, __shfl_xor(m, off, 64));
  float e = __expf(v - m);
#pragma unroll
  for (int off = 32; off > 0; off >>= 1)
    e += __shfl_xor(e, off, 64);
  if (j == 0) totals[b] = m + __logf(e);
}

// ---------------- K5: gold path score per b ----------------------------------
__global__ __launch_bounds__(256) void k_real(const float* __restrict__ logits,
                                              const int* __restrict__ tags,
                                              const float* __restrict__ trans,
                                              float* __restrict__ reals) {
  __shared__ float red[256];
  int b = blockIdx.x;
  float acc = 0.f;
  for (int s = threadIdx.x; s < S_; s += 256) {
    int tg = tags[(size_t)b * S_ + s];
    int pv = (s == 0) ? START_ : tags[(size_t)b * S_ + s - 1];
    acc += logits[((size_t)b * S_ + s) * T_ + tg] + trans[pv * T_ + tg];
  }
  red[threadIdx.x] = acc;
  __syncthreads();
  for (int off = 128; off > 0; off >>= 1) {
    if (threadIdx.x < off) red[threadIdx.x] += red[threadIdx.x + off];
    __syncthreads();
  }
  if (threadIdx.x == 0)
    reals[b] = red[0] + trans[tags[(size_t)b * S_ + S_ - 1] * T_ + STOP_];
}

// ---------------- K6: out = sum_b totals - reals -----------------------------
__global__ __launch_bounds__(256) void k_final(const float* __restrict__ totals,
                                               const float* __restrict__ reals,
                                               float* __restrict__ out) {
  __shared__ float red[256];
  float acc = 0.f;
  for (int b = threadIdx.x; b < B_; b += 256) acc += totals[b] - reals[b];
  red[threadIdx.x] = acc;
  __syncthreads();
  for (int off = 128; off > 0; off >>= 1) {
    if (threadIdx.x < off) red[threadIdx.x] += red[threadIdx.x + off];
    __syncthreads();
  }
  if (threadIdx.x == 0) out[0] = red[0];
}

// ws: feat(bf16) 67,108,864 | logits 26,214,400 | WoutP 8,192 |
//     Wcomb 196,608 | embP 1,120,000 | totals 2,048 | reals 2,048  (~94.6 MiB)
extern "C" void kernel_launch(void* const* d_in, const int* in_sizes, int n_in,
                              void* d_out, int out_size, void* d_ws, size_t ws_size,
                              hipStream_t stream) {
  const int*   sentences = (const int*)d_in[0];
  const int*   tags  = (const int*)d_in[1];
  const float* embed = (const float*)d_in[2];
  const float* Wih_f = (const float*)d_in[3];
  const float* Whh_f = (const float*)d_in[4];
  const float* bih_f = (const float*)d_in[5];
  const float* bhh_f = (const float*)d_in[6];
  const float* Wih_b = (const float*)d_in[7];
  const float* Whh_b = (const float*)d_in[8];
  const float* bih_b = (const float*)d_in[9];
  const float* bhh_b = (const float*)d_in[10];
  const float* h0    = (const float*)d_in[11];
  const float* c0    = (const float*)d_in[12];
  const float* Wout  = (const float*)d_in[13];
  const float* bout  = (const float*)d_in[14];
  const float* trans = (const float*)d_in[15];

  char* ws = (char*)d_ws;
  __hip_bfloat16* feat  = (__hip_bfloat16*)(ws);
  float* logits         = (float*)(ws + 67108864);
  __hip_bfloat16* WoutP = (__hip_bfloat16*)(ws + 67108864 + 26214400);
  _Float16* Wcomb       = (_Float16*)(ws + 67108864 + 26214400 + 8192);
  _Float16* embP        = (_Float16*)(ws + 67108864 + 26214400 + 8192 + 196608);
  float* totals         = (float*)(ws + 67108864 + 26214400 + 8192 + 196608 + 1120000);
  float* reals          = totals + B_;
  float* out            = (float*)d_out;

  k_prep_w<<<384, 256, 0, stream>>>(Whh_f, Wih_f, Whh_b, Wih_b, Wcomb);
  k_prep_e<<<2188, 256, 0, stream>>>(embed, embP);
  k_prep_o<<<16, 256, 0, stream>>>(Wout, WoutP);
  k_lstm<<<64, 256, 0, stream>>>(sentences, embP, Wcomb,
                                 bih_f, bhh_f, bih_b, bhh_b, h0, c0, feat);
  k_logits<<<4096, 256, 0, stream>>>(feat, WoutP, bout, logits);
  k_crf<<<512, 64, 0, stream>>>(logits, trans, totals);
  k_real<<<512, 256, 0, stream>>>(logits, tags, trans, reals);
  k_final<<<1, 256, 0, stream>>>(totals, reals, out);
}

// Round 7
// 578.650 us; speedup vs baseline: 1.4417x; 1.4417x over previous
//
#include <hip/hip_runtime.h>
#include <hip/hip_bf16.h>
#include <cstdint>

#define B_ 512
#define S_ 512
#define V_ 5000
#define E_ 100
#define HD_ 64
#define T_ 25
#define START_ 1
#define STOP_ 2

typedef __attribute__((ext_vector_type(8))) short short8;
typedef __attribute__((ext_vector_type(4))) float f32x4;
typedef _Float16 h2 __attribute__((ext_vector_type(2)));

// v_pk_fma_f16: 2 f16 MACs / instr, f16 accumulate (VOP3P, guaranteed on gfx950)
__device__ inline h2 pkfma(uint32_t w, uint32_t h, h2 c) {
  return __builtin_elementwise_fma(__builtin_bit_cast(h2, w),
                                   __builtin_bit_cast(h2, h), c);
}

__device__ inline float sigm(float x) { return 1.0f / (1.0f + __expf(-x)); }
__device__ inline float tanh_(float x) { return 1.0f - 2.0f / (1.0f + __expf(2.0f * x)); }

// ---------------- K1: P[v][j*4+g] = embed[v] . Wih[g*64+j], per dir ----------
// k_lstm lane j loads float4 = (x_i, x_f, x_g, x_o) for hidden j, coalesced.
__global__ __launch_bounds__(256) void k_proj(const float* __restrict__ embed,
                                              const float* __restrict__ Wf,
                                              const float* __restrict__ Wb,
                                              float* __restrict__ Pf,
                                              float* __restrict__ Pb) {
  __shared__ __align__(16) float embS[16 * E_];
  int v0 = blockIdx.x * 16;
  const float* Wih = blockIdx.y ? Wb : Wf;
  float* P = blockIdx.y ? Pb : Pf;
  int nv = V_ - v0; if (nv > 16) nv = 16;
  for (int idx = threadIdx.x; idx < nv * E_; idx += 256)
    embS[idx] = embed[v0 * E_ + idx];
  __syncthreads();
  int u = threadIdx.x;
  float acc[16];
#pragma unroll
  for (int i = 0; i < 16; i++) acc[i] = 0.f;
  const float4* W4 = (const float4*)(Wih + u * E_);
  const float4* e4 = (const float4*)embS;
#pragma unroll 5
  for (int q = 0; q < 25; q++) {
    float4 w = W4[q];
#pragma unroll
    for (int vi = 0; vi < 16; vi++) {
      float4 e = e4[vi * 25 + q];
      acc[vi] += w.x * e.x + w.y * e.y + w.z * e.z + w.w * e.w;
    }
  }
  int pk = (u & 63) * 4 + (u >> 6);   // hidden j -> float4 slot, gate -> comp
  for (int vi = 0; vi < nv; vi++)
    P[(size_t)(v0 + vi) * 256 + pk] = acc[vi];
}

// ---------------- K1b: WoutPad[32][128] bf16 (rows >= 25 zero) ----------------
__global__ __launch_bounds__(256) void k_prep(const float* __restrict__ Wout,
                                              __hip_bfloat16* __restrict__ WoutP) {
  int idx = blockIdx.x * 256 + threadIdx.x;
  if (idx < 32 * 128) {
    int r = idx >> 7, c = idx & 127;
    float v = (r < T_) ? Wout[r * 128 + c] : 0.f;
    WoutP[idx] = __float2bfloat16(v);
  }
}

// ---------------- K2: BiLSTM: 1 wave = 1 seq, no barriers (r3 structure) -----
// Single change vs r3/r5: the 256 MACs/lane use v_pk_fma_f16 (1 instr / 2 MACs,
// f16 accum) instead of fdot2 (which the VALU arithmetic of r3/r5 says was
// being expanded ~4x). Weight footprint unchanged; AGPR demotion accepted
// (1-cyc moves). No waves_per_eu pin (r5 showed it neutral/harmful).
__global__ __launch_bounds__(64) void k_lstm(
    const int* __restrict__ sentences,
    const float* __restrict__ Pf, const float* __restrict__ Pb,
    const float* __restrict__ Whh_f, const float* __restrict__ Whh_b,
    const float* __restrict__ bih_f, const float* __restrict__ bhh_f,
    const float* __restrict__ bih_b, const float* __restrict__ bhh_b,
    const float* __restrict__ h0, const float* __restrict__ c0,
    __hip_bfloat16* __restrict__ feat) {
  int j = threadIdx.x;                 // 0..63 = hidden unit
  int seq = blockIdx.x;                // 0..1023
  int be = seq & (B_ - 1);
  int d = seq >> 9;                    // 0 fwd, 1 bwd
  const float* P   = d ? Pb : Pf;
  const float* Whh = d ? Whh_b : Whh_f;
  const float* bih = d ? bih_b : bih_f;
  const float* bhh = d ? bhh_b : bhh_f;

  __shared__ __align__(16) uint32_t hS[32];   // 64 f16 h values

  // Whh rows u = g*64 + j as f16 pairs: wp[g][kp] = (W[u][2kp], W[u][2kp+1])
  uint32_t wp[4][32];
  float bg[4];
#pragma unroll
  for (int g = 0; g < 4; g++) {
    int u = g * 64 + j;
    const float4* rp = (const float4*)(Whh + (size_t)u * HD_);
#pragma unroll
    for (int q = 0; q < 16; q++) {
      float4 a = rp[q];
      union { _Float16 h[2]; uint32_t u32; } p0, p1;
      p0.h[0] = (_Float16)a.x; p0.h[1] = (_Float16)a.y;
      p1.h[0] = (_Float16)a.z; p1.h[1] = (_Float16)a.w;
      wp[g][2 * q] = p0.u32; wp[g][2 * q + 1] = p1.u32;
    }
    bg[g] = bih[u] + bhh[u];
  }
  float c = c0[(d * B_ + be) * HD_ + j];
  ((_Float16*)hS)[j] = (_Float16)h0[(d * B_ + be) * HD_ + j];
  asm volatile("s_waitcnt lgkmcnt(0)" ::: "memory");

  const int* sent = sentences + (size_t)be * S_;
  int tt0 = d ? (S_ - 1) : 0;
  int stp = d ? -1 : 1;
  int tok1 = sent[tt0];
  const float4* P4 = (const float4*)P;
  float4 x = P4[(size_t)tok1 * 64 + j];
  tok1 = sent[tt0 + stp];
  const uint4* hS4 = (const uint4*)hS;

  for (int t = 0; t < S_; t++) {
    int tt = tt0 + stp * t;
    float4 xn = x;
    if (t + 1 < S_) xn = P4[(size_t)tok1 * 64 + j];
    int tok2 = tok1;
    if (t + 2 < S_) tok2 = sent[tt + 2 * stp];

    h2 ac[4][2];
#pragma unroll
    for (int g = 0; g < 4; g++) {
      ac[g][0] = (h2)(_Float16)0.f;
      ac[g][1] = (h2)(_Float16)0.f;
    }
#pragma unroll
    for (int q = 0; q < 8; q++) {
      uint4 hv = hS4[q];
      int kp = 4 * q;
#pragma unroll
      for (int g = 0; g < 4; g++) {
        ac[g][0] = pkfma(wp[g][kp + 0], hv.x, ac[g][0]);
        ac[g][1] = pkfma(wp[g][kp + 1], hv.y, ac[g][1]);
        ac[g][0] = pkfma(wp[g][kp + 2], hv.z, ac[g][0]);
        ac[g][1] = pkfma(wp[g][kp + 3], hv.w, ac[g][1]);
      }
    }
    h2 s0 = ac[0][0] + ac[0][1];       // v_pk_add_f16
    h2 s1 = ac[1][0] + ac[1][1];
    h2 s2 = ac[2][0] + ac[2][1];
    h2 s3 = ac[3][0] + ac[3][1];
    float zi = (float)s0[0] + (float)s0[1] + bg[0] + x.x;
    float zf = (float)s1[0] + (float)s1[1] + bg[1] + x.y;
    float zg = (float)s2[0] + (float)s2[1] + bg[2] + x.z;
    float zo = (float)s3[0] + (float)s3[1] + bg[3] + x.w;
    c = sigm(zf) * c + sigm(zi) * tanh_(zg);
    float hh = sigm(zo) * tanh_(c);
    feat[((size_t)be * S_ + tt) * 128 + d * 64 + j] = __float2bfloat16(hh);
    ((_Float16*)hS)[j] = (_Float16)hh;
    asm volatile("s_waitcnt lgkmcnt(0)" ::: "memory");
    x = xn;
    tok1 = tok2;
  }
}

// ---------------- K3: logits = feat . WoutP^T + bout via MFMA -----------------
__global__ __launch_bounds__(256) void k_logits(const __hip_bfloat16* __restrict__ feat,
                                                const __hip_bfloat16* __restrict__ WoutP,
                                                const float* __restrict__ bout,
                                                float* __restrict__ logits) {
  int w = threadIdx.x >> 6, l = threadIdx.x & 63;
  size_t r0 = ((size_t)blockIdx.x * 4 + w) * 16;
  int mrow = l & 15, kg = l >> 4;
  short8 bfr[2][4];
#pragma unroll
  for (int nt = 0; nt < 2; nt++) {
    int n = nt * 16 + mrow;
#pragma unroll
    for (int kb = 0; kb < 4; kb++)
      bfr[nt][kb] = *(const short8*)(WoutP + n * 128 + kb * 32 + kg * 8);
  }
  f32x4 acc[2];
#pragma unroll
  for (int nt = 0; nt < 2; nt++) {
    int col = nt * 16 + mrow;
    float bb = (col < T_) ? bout[col] : 0.f;
    acc[nt] = (f32x4){bb, bb, bb, bb};
  }
#pragma unroll
  for (int kb = 0; kb < 4; kb++) {
    short8 a = *(const short8*)(feat + (r0 + mrow) * 128 + kb * 32 + kg * 8);
    acc[0] = __builtin_amdgcn_mfma_f32_16x16x32_bf16(a, bfr[0][kb], acc[0], 0, 0, 0);
    acc[1] = __builtin_amdgcn_mfma_f32_16x16x32_bf16(a, bfr[1][kb], acc[1], 0, 0, 0);
  }
#pragma unroll
  for (int nt = 0; nt < 2; nt++) {
    int col = nt * 16 + mrow;
    if (col < T_) {
#pragma unroll
      for (int q = 0; q < 4; q++) {
        int row = kg * 4 + q;
        logits[(r0 + row) * T_ + col] = acc[nt][q];
      }
    }
  }
}

// ---------------- K4: CRF forward, 1 wave = 1 batch elem ---------------------
__global__ __launch_bounds__(64) void k_crf(const float* __restrict__ logits,
                                            const float* __restrict__ trans,
                                            float* __restrict__ totals) {
  int j = threadIdx.x;
  int b = blockIdx.x;
  bool act = j < T_;
  __shared__ __align__(16) float qS[32];
  float Ecol[T_];
#pragma unroll
  for (int i = 0; i < T_; i++)
    Ecol[i] = act ? __expf(trans[i * T_ + j]) : 0.f;
  if (j >= T_ && j < 32) qS[j] = 0.f;
  float tstop = act ? trans[j * T_ + STOP_] : 0.f;
  float prev = act ? 0.f : -INFINITY;
  const float* lg = logits + (size_t)b * S_ * T_;
  float ltn = act ? lg[j] : 0.f;
  asm volatile("s_waitcnt lgkmcnt(0)" ::: "memory");
  for (int t = 0; t < S_; t++) {
    float lt = ltn;
    if (t + 1 < S_) ltn = act ? lg[(size_t)(t + 1) * T_ + j] : 0.f;
    float m = __builtin_bit_cast(float,
        __builtin_amdgcn_readfirstlane(__builtin_bit_cast(int, prev)));
    float q = __expf(prev - m);
    if (act) qS[j] = q;
    asm volatile("s_waitcnt lgkmcnt(0)" ::: "memory");
    const float4* q4 = (const float4*)qS;
    float4 qv0 = q4[0], qv1 = q4[1], qv2 = q4[2], qv3 = q4[3];
    float4 qv4 = q4[4], qv5 = q4[5], qv6 = q4[6];
    float s0, s1, s2, s3;
    s0 = qv0.x * Ecol[0];  s1 = qv0.y * Ecol[1];
    s2 = qv0.z * Ecol[2];  s3 = qv0.w * Ecol[3];
    s0 += qv1.x * Ecol[4];  s1 += qv1.y * Ecol[5];
    s2 += qv1.z * Ecol[6];  s3 += qv1.w * Ecol[7];
    s0 += qv2.x * Ecol[8];  s1 += qv2.y * Ecol[9];
    s2 += qv2.z * Ecol[10]; s3 += qv2.w * Ecol[11];
    s0 += qv3.x * Ecol[12]; s1 += qv3.y * Ecol[13];
    s2 += qv3.z * Ecol[14]; s3 += qv3.w * Ecol[15];
    s0 += qv4.x * Ecol[16]; s1 += qv4.y * Ecol[17];
    s2 += qv4.z * Ecol[18]; s3 += qv4.w * Ecol[19];
    s0 += qv5.x * Ecol[20]; s1 += qv5.y * Ecol[21];
    s2 += qv5.z * Ecol[22]; s3 += qv5.w * Ecol[23];
    s0 += qv6.x * Ecol[24];
    float s = (s0 + s1) + (s2 + s3);
    prev = lt + m + __logf(s);
    if (!act) prev = -INFINITY;
  }
  float v = prev + tstop;
  float m = v;
#pragma unroll
  for (int off = 32; off > 0; off >>= 1)
    m = fmaxf(m, __shfl_xor(m, off, 64));
  float e = __expf(v - m);
#pragma unroll
  for (int off = 32; off > 0; off >>= 1)
    e += __shfl_xor(e, off, 64);
  if (j == 0) totals[b] = m + __logf(e);
}

// ---------------- K5: gold path score per b ----------------------------------
__global__ __launch_bounds__(256) void k_real(const float* __restrict__ logits,
                                              const int* __restrict__ tags,
                                              const float* __restrict__ trans,
                                              float* __restrict__ reals) {
  __shared__ float red[256];
  int b = blockIdx.x;
  float acc = 0.f;
  for (int s = threadIdx.x; s < S_; s += 256) {
    int tg = tags[(size_t)b * S_ + s];
    int pv = (s == 0) ? START_ : tags[(size_t)b * S_ + s - 1];
    acc += logits[((size_t)b * S_ + s) * T_ + tg] + trans[pv * T_ + tg];
  }
  red[threadIdx.x] = acc;
  __syncthreads();
  for (int off = 128; off > 0; off >>= 1) {
    if (threadIdx.x < off) red[threadIdx.x] += red[threadIdx.x + off];
    __syncthreads();
  }
  if (threadIdx.x == 0)
    reals[b] = red[0] + trans[tags[(size_t)b * S_ + S_ - 1] * T_ + STOP_];
}

// ---------------- K6: out = sum_b totals - reals -----------------------------
__global__ __launch_bounds__(256) void k_final(const float* __restrict__ totals,
                                               const float* __restrict__ reals,
                                               float* __restrict__ out) {
  __shared__ float red[256];
  float acc = 0.f;
  for (int b = threadIdx.x; b < B_; b += 256) acc += totals[b] - reals[b];
  red[threadIdx.x] = acc;
  __syncthreads();
  for (int off = 128; off > 0; off >>= 1) {
    if (threadIdx.x < off) red[threadIdx.x] += red[threadIdx.x + off];
    __syncthreads();
  }
  if (threadIdx.x == 0) out[0] = red[0];
}

// ws: Pf 5,120,000 | Pb 5,120,000 | feat(bf16) 67,108,864 | logits 26,214,400
//   | WoutP 8,192 | totals 2,048 | reals 2,048
extern "C" void kernel_launch(void* const* d_in, const int* in_sizes, int n_in,
                              void* d_out, int out_size, void* d_ws, size_t ws_size,
                              hipStream_t stream) {
  const int*   sentences = (const int*)d_in[0];
  const int*   tags  = (const int*)d_in[1];
  const float* embed = (const float*)d_in[2];
  const float* Wih_f = (const float*)d_in[3];
  const float* Whh_f = (const float*)d_in[4];
  const float* bih_f = (const float*)d_in[5];
  const float* bhh_f = (const float*)d_in[6];
  const float* Wih_b = (const float*)d_in[7];
  const float* Whh_b = (const float*)d_in[8];
  const float* bih_b = (const float*)d_in[9];
  const float* bhh_b = (const float*)d_in[10];
  const float* h0    = (const float*)d_in[11];
  const float* c0    = (const float*)d_in[12];
  const float* Wout  = (const float*)d_in[13];
  const float* bout  = (const float*)d_in[14];
  const float* trans = (const float*)d_in[15];

  char* ws = (char*)d_ws;
  float* Pf = (float*)(ws);
  float* Pb = (float*)(ws + 5120000);
  __hip_bfloat16* feat = (__hip_bfloat16*)(ws + 10240000);
  float* logits = (float*)(ws + 10240000 + 67108864);
  __hip_bfloat16* WoutP = (__hip_bfloat16*)(ws + 10240000 + 67108864 + 26214400);
  float* totals = (float*)(ws + 10240000 + 67108864 + 26214400 + 8192);
  float* reals  = totals + B_;
  float* out    = (float*)d_out;

  k_proj<<<dim3(313, 2), 256, 0, stream>>>(embed, Wih_f, Wih_b, Pf, Pb);
  k_prep<<<16, 256, 0, stream>>>(Wout, WoutP);
  k_lstm<<<1024, 64, 0, stream>>>(sentences, Pf, Pb, Whh_f, Whh_b,
                                  bih_f, bhh_f, bih_b, bhh_b, h0, c0, feat);
  k_logits<<<4096, 256, 0, stream>>>(feat, WoutP, bout, logits);
  k_crf<<<512, 64, 0, stream>>>(logits, trans, totals);
  k_real<<<512, 256, 0, stream>>>(logits, tags, trans, reals);
  k_final<<<1, 256, 0, stream>>>(totals, reals, out);
}